// Round 1
// baseline (442.779 us; speedup 1.0000x reference)
//
#include <hip/hip_runtime.h>

// WindowAttention, R4 (= R3 + vectorized K/Q staging): the 64 scalar 4B
// global loads/thread for K/Q fragments (quarter-line requests) are replaced
// by cooperative float4 full-line staging through XOR-swizzled per-wave LDS.
// Layout per tensor: [32ch][16 units x 4 keys], stored unit = (key>>2) ^ P,
// P(ch) = ((ch>>3)<<2)|(ch&3)  -> fragment ds_read_u16 hits 32 distinct
// banks (2 lanes/bank = free). LDS phases: {K,Q} -> GEMM1 -> {V over dead
// K/Q union} -> GEMM2 (3 barriers). V path / softmax / GEMM2 / epilogue
// are unchanged from the 483.8us-verified R3.

typedef __attribute__((ext_vector_type(8))) _Float16 half8;
typedef __attribute__((ext_vector_type(2))) __fp16 fp16x2;  // cvt_pkrtz return type
typedef __attribute__((ext_vector_type(4))) float f32x4;
typedef unsigned int u32;

#define WSZ 8
#define HGT 128
#define WID 128
#define HWSZ (HGT * WID)
#define CCH 256
#define NHEADS 8
#define HDIM 32
#define VP 72   // v row stride in halves: 144B rows, 16B-aligned b128 frag reads

union __attribute__((aligned(16))) WaveBuf {
  // GEMM1 phase: K and Q, each [32ch][72 halves] (16 swizzled 4-key units/row)
  struct { _Float16 k[32 * 72]; _Float16 q[32 * 72]; } kq;   // 9216 B
  // GEMM2 phase: V [ch][key] + disjoint output-transpose buffer
  struct { _Float16 v[32 * VP + 8]; float o[64 * 17]; } vo;  // 8992 B
};

__device__ __forceinline__ void lds_fence() {
  asm volatile("s_waitcnt lgkmcnt(0)" ::: "memory");
}
__device__ __forceinline__ u32 h2u(fp16x2 h) {
  union { fp16x2 h; u32 u; } c; c.h = h; return c.u;
}

__global__ void __launch_bounds__(256, 4) wattn_kernel(
    const float* __restrict__ qg, const float* __restrict__ kg,
    const float* __restrict__ vg, const float* __restrict__ btg,
    const int* __restrict__ shiftp, float* __restrict__ outg) {

  __shared__ WaveBuf wb[4];
  __shared__ float bias_lds[226];

  const int tid  = threadIdx.x;
  const int wave = tid >> 6;
  const int lane = tid & 63;
  const int quad = lane >> 4;
  const int c16  = lane & 15;

  // grid: bid = ((b*8 + head)*16 + wh)*4 + wg ; block owns ww = wg*4 + {0..3}
  const int bid  = blockIdx.x;
  const int wg   = bid & 3;
  const int wh   = (bid >> 2) & 15;
  const int th   = bid >> 6;
  const int head = th & (NHEADS - 1);
  const int b    = th >> 3;
  const int ww   = wg * 4 + wave;

  const int sh   = *shiftp;
  const int base = (b * CCH + head * HDIM) * HWSZ;

  // bias table for this head (shared across the 4 waves), pre-scaled by log2(e)
  for (int t = tid; t < 225; t += 256)
    bias_lds[t] = btg[t * NHEADS + head] * 1.44269504088896f;

  // ---- cooperative K staging: float4 full-line loads, f16 pack, swizzled
  //      uint2 writes into [ch][unit^P] ----
  {
    const float* kb_g = kg + base + (wh * WSZ) * WID + wg * 32;
#pragma unroll
    for (int i = 0; i < 8; ++i) {
      const int flat = i * 256 + tid;     // 0..2047
      const int col4 = flat & 7;
      const int row  = (flat >> 3) & 7;
      const int ch   = flat >> 6;
      const f32x4 f = *(const f32x4*)(kb_g + ch * HWSZ + row * WID + col4 * 4);
      const int w  = col4 >> 1;                       // target window in group
      const int un = (2 * row + (col4 & 1)) ^ (((ch >> 3) << 2) | (ch & 3));
      uint2 u;
      u.x = h2u(__builtin_amdgcn_cvt_pkrtz(f.x, f.y));
      u.y = h2u(__builtin_amdgcn_cvt_pkrtz(f.z, f.w));
      *(uint2*)&wb[w].kq.k[ch * 72 + un * 4] = u;
    }
  }

  // ---- cooperative Q staging (shifted source coords). Vector path valid
  //      whenever sh%4==0 (groups stay 16B-contiguous mod the roll). ----
  if ((sh & 3) == 0) {
#pragma unroll
    for (int i = 0; i < 8; ++i) {
      const int flat = i * 256 + tid;
      const int col4 = flat & 7;
      const int row  = (flat >> 3) & 7;
      const int ch   = flat >> 6;
      const int grow = (wh * WSZ + row + sh) & (HGT - 1);
      const int gc0  = (wg * 32 + col4 * 4 + sh) & (WID - 1);
      const f32x4 f = *(const f32x4*)(qg + base + ch * HWSZ + grow * WID + gc0);
      const int w  = col4 >> 1;
      const int un = (2 * row + (col4 & 1)) ^ (((ch >> 3) << 2) | (ch & 3));
      uint2 u;
      u.x = h2u(__builtin_amdgcn_cvt_pkrtz(f.x, f.y));
      u.y = h2u(__builtin_amdgcn_cvt_pkrtz(f.z, f.w));
      *(uint2*)&wb[w].kq.q[ch * 72 + un * 4] = u;
    }
  } else {  // general-shift fallback: per-element wrap, scalar loads
#pragma unroll
    for (int i = 0; i < 8; ++i) {
      const int flat = i * 256 + tid;
      const int col4 = flat & 7;
      const int row  = (flat >> 3) & 7;
      const int ch   = flat >> 6;
      const int grow = (wh * WSZ + row + sh) & (HGT - 1);
      const float* qrow = qg + base + ch * HWSZ + grow * WID;
      const int cb = wg * 32 + col4 * 4 + sh;
      const float x0 = qrow[(cb + 0) & (WID - 1)];
      const float x1 = qrow[(cb + 1) & (WID - 1)];
      const float x2 = qrow[(cb + 2) & (WID - 1)];
      const float x3 = qrow[(cb + 3) & (WID - 1)];
      const int w  = col4 >> 1;
      const int un = (2 * row + (col4 & 1)) ^ (((ch >> 3) << 2) | (ch & 3));
      uint2 u;
      u.x = h2u(__builtin_amdgcn_cvt_pkrtz(x0, x1));
      u.y = h2u(__builtin_amdgcn_cvt_pkrtz(x2, x3));
      *(uint2*)&wb[w].kq.q[ch * 72 + un * 4] = u;
    }
  }

  __syncthreads();  // K,Q staged for all 4 windows

  // ---- fragment reads: aK rows=key (A-op), bQ cols=query (B-op).
  //      pos(ch,key) = ch*72 + ((key>>2)^P)*4 + (key&3); key = t*16+c16.
  //      Bank check: 4j + 2((c16>>2)^(j&3)) + 8(t^quad) + ((c16&3)>>1)
  //      covers 32 distinct banks, 2 lanes each -> conflict-free. ----
  half8 aK[4], bQ[4];
  {
    const _Float16* kb = wb[wave].kq.k;
    const _Float16* qb = wb[wave].kq.q;
#pragma unroll
    for (int j = 0; j < 8; ++j) {
      const int ch = quad * 8 + j;
      const int P  = (quad << 2) | (j & 3);
      const int rb = ch * 72 + (c16 & 3);
#pragma unroll
      for (int t = 0; t < 4; ++t) {
        const int un = ((t * 4 + (c16 >> 2)) ^ P) * 4;
        aK[t][j] = kb[rb + un];
        bQ[t][j] = qb[rb + un];
      }
    }
  }

  const f32x4 zero4 = {0.f, 0.f, 0.f, 0.f};
  const float scale2 = 0.17677669529663687f * 1.44269504088896f; // rsqrt(32)*log2e

  // bias row offsets for this lane's keys: r = tr*16 + quad*4 + reg
  int tsub[4];
#pragma unroll
  for (int reg = 0; reg < 4; ++reg) {
    const int t = quad * 4 + reg;
    tsub[reg] = (t >> 3) * 15 + (t & 7);
  }

  u32 pk01[4][4], pk23[4][4];  // [tr][tc]: packed f16 pairs of exp(S^T) regs {0,1},{2,3}
  float rinv[4];

  // ---- GEMM1 streamed per query tile tc: S^T col-tile -> softmax col-sum -> pack ----
#pragma unroll
  for (int tc = 0; tc < 4; ++tc) {
    f32x4 sc[4];
#pragma unroll
    for (int tr = 0; tr < 4; ++tr)
      sc[tr] = __builtin_amdgcn_mfma_f32_16x16x32_f16(aK[tr], bQ[tc], zero4, 0, 0, 0);
    const int q64 = tc * 16 + c16;
    const int qb  = ((q64 >> 3) + 7) * 15 + (q64 & 7) + 7;
    float e[4][4], s = 0.f;
#pragma unroll
    for (int tr = 0; tr < 4; ++tr)
#pragma unroll
      for (int reg = 0; reg < 4; ++reg) {
        const float ev = __builtin_amdgcn_exp2f(
            fmaf(sc[tr][reg], scale2, bias_lds[qb - tr * 30 - tsub[reg]]));
        e[tr][reg] = ev; s += ev;
      }
    // column sum: lane covers 16 keys; quads hold disjoint key quartets
    s += __shfl_xor(s, 16); s += __shfl_xor(s, 32);
    rinv[tc] = __builtin_amdgcn_rcpf(s);
#pragma unroll
    for (int tr = 0; tr < 4; ++tr) {
      pk01[tr][tc] = h2u(__builtin_amdgcn_cvt_pkrtz(e[tr][0], e[tr][1]));
      pk23[tr][tc] = h2u(__builtin_amdgcn_cvt_pkrtz(e[tr][2], e[tr][3]));
    }
  }

  __syncthreads();  // all waves done with K/Q LDS; V may overwrite the union

  // ---- cooperative V staging: float4 loads = full 128B lines, f16 packed
  //      into per-wave [ch][key] (identical to R3) ----
  {
    const float* vb = vg + base + (wh * WSZ) * WID + wg * 32;
#pragma unroll
    for (int i = 0; i < 8; ++i) {
      const int flat = i * 256 + tid;     // 0..2047
      const int col4 = flat & 7;
      const int row  = (flat >> 3) & 7;
      const int ch   = flat >> 6;
      const f32x4 f = *(const f32x4*)(vb + ch * HWSZ + row * WID + col4 * 4);
      const int w  = col4 >> 1;                  // target window within group
      const int kb = row * 8 + (col4 & 1) * 4;   // key index of first of 4 cols
      uint2 u;
      u.x = h2u(__builtin_amdgcn_cvt_pkrtz(f.x, f.y));
      u.y = h2u(__builtin_amdgcn_cvt_pkrtz(f.z, f.w));
      *(uint2*)&wb[w].vo.v[ch * VP + kb] = u;
    }
  }

  __syncthreads();  // V staged

  // ---- GEMM2: O^T[ch][q] = V^T (A, LDS) x P^T (B, cross-quad shuffles) ----
  half8 aV[2][2];
#pragma unroll
  for (int mt = 0; mt < 2; ++mt)
#pragma unroll
    for (int kc = 0; kc < 2; ++kc)
      aV[mt][kc] = *(const half8*)&wb[wave].vo.v[(mt * 16 + c16) * VP + kc * 32 + quad * 8];

  // B-frag element j needs pexp[tr=kc*2+(quad>>1)][nt][reg=j&3] from lane
  // (2*(quad&1)+(j>>2))*16 + c16 : same c16, compile-time reg -> shfl + select.
  const int s0 = ((lane & 16) << 1) | c16;
  const int s1 = s0 + 16;
  const bool hi = (lane & 32) != 0;

  f32x4 of2[2][4];
#pragma unroll
  for (int mt = 0; mt < 2; ++mt)
#pragma unroll
    for (int nt = 0; nt < 4; ++nt) of2[mt][nt] = zero4;

#pragma unroll
  for (int nt = 0; nt < 4; ++nt)
#pragma unroll
    for (int kc = 0; kc < 2; ++kc) {
      const int t0 = kc * 2, t1 = kc * 2 + 1;
      const u32 w0a = __shfl(pk01[t0][nt], s0), w0b = __shfl(pk01[t1][nt], s0);
      const u32 w1a = __shfl(pk23[t0][nt], s0), w1b = __shfl(pk23[t1][nt], s0);
      const u32 w2a = __shfl(pk01[t0][nt], s1), w2b = __shfl(pk01[t1][nt], s1);
      const u32 w3a = __shfl(pk23[t0][nt], s1), w3b = __shfl(pk23[t1][nt], s1);
      union { u32 u[4]; half8 h; } bp;
      bp.u[0] = hi ? w0b : w0a;
      bp.u[1] = hi ? w1b : w1a;
      bp.u[2] = hi ? w2b : w2a;
      bp.u[3] = hi ? w3b : w3a;
#pragma unroll
      for (int mt = 0; mt < 2; ++mt)
        of2[mt][nt] = __builtin_amdgcn_mfma_f32_16x16x32_f16(aV[mt][kc], bp.h,
                                                             of2[mt][nt], 0, 0, 0);
    }

  // ---- epilogue: normalize by rinv[query col], transpose via per-wave LDS
  //      (disjoint from V; wave-local fences only), coalesced stores ----
  const int hq = (wh * WSZ + (lane >> 3) + sh) & (HGT - 1);
  const int wq = (ww * WSZ + (lane & 7) + sh) & (WID - 1);
  float* ob = outg + base + hq * WID + wq;
  float* obuf = wb[wave].vo.o;

#pragma unroll
  for (int mt = 0; mt < 2; ++mt) {
    lds_fence();
#pragma unroll
    for (int nt = 0; nt < 4; ++nt)
#pragma unroll
      for (int reg = 0; reg < 4; ++reg)
        obuf[(nt * 16 + c16) * 17 + quad * 4 + reg] = of2[mt][nt][reg] * rinv[nt];
    lds_fence();
#pragma unroll
    for (int c = 0; c < 16; ++c)
      ob[(mt * 16 + c) * HWSZ] = obuf[lane * 17 + c];
  }
}

extern "C" void kernel_launch(void* const* d_in, const int* in_sizes, int n_in,
                              void* d_out, int out_size, void* d_ws, size_t ws_size,
                              hipStream_t stream) {
  const float* q  = (const float*)d_in[0];
  const float* k  = (const float*)d_in[1];
  const float* v  = (const float*)d_in[2];
  const float* bt = (const float*)d_in[3];
  const int*   sh = (const int*)d_in[4];
  float* out = (float*)d_out;

  // 8b x 8heads x 16wh x 4 window-groups = 4096 blocks x 256 threads
  dim3 grid(4096), block(256);
  hipLaunchKernelGGL(wattn_kernel, grid, block, 0, stream, q, k, v, bt, sh, out);
}

// Round 2
// 442.098 us; speedup vs baseline: 1.0015x; 1.0015x over previous
//
#include <hip/hip_runtime.h>

// WindowAttention, R5 (= R4 + V register prefetch, T14 async-STAGE split):
// the 8 V float4 loads are issued at kernel start into registers, overlapping
// the K/Q staging loads (24 outstanding loads/thread instead of 16), packed
// to f16 uint2 before barrier 1, and committed to LDS after GEMM1 with pure
// ds_writes. This removes the second exposed ~900-cycle HBM latency round
// per block that capped delivered BW at 29% of peak (R4: 187us/dispatch,
// 2.33 TB/s, VALUBusy 12%, MfmaUtil 1.8% -> latency-bound).

typedef __attribute__((ext_vector_type(8))) _Float16 half8;
typedef __attribute__((ext_vector_type(2))) __fp16 fp16x2;  // cvt_pkrtz return type
typedef __attribute__((ext_vector_type(4))) float f32x4;
typedef unsigned int u32;

#define WSZ 8
#define HGT 128
#define WID 128
#define HWSZ (HGT * WID)
#define CCH 256
#define NHEADS 8
#define HDIM 32
#define VP 72   // v row stride in halves: 144B rows, 16B-aligned b128 frag reads

union __attribute__((aligned(16))) WaveBuf {
  // GEMM1 phase: K and Q, each [32ch][72 halves] (16 swizzled 4-key units/row)
  struct { _Float16 k[32 * 72]; _Float16 q[32 * 72]; } kq;   // 9216 B
  // GEMM2 phase: V [ch][key] + disjoint output-transpose buffer
  struct { _Float16 v[32 * VP + 8]; float o[64 * 17]; } vo;  // 8976 B
};

__device__ __forceinline__ void lds_fence() {
  asm volatile("s_waitcnt lgkmcnt(0)" ::: "memory");
}
__device__ __forceinline__ u32 h2u(fp16x2 h) {
  union { fp16x2 h; u32 u; } c; c.h = h; return c.u;
}

__global__ void __launch_bounds__(256, 4) wattn_kernel(
    const float* __restrict__ qg, const float* __restrict__ kg,
    const float* __restrict__ vg, const float* __restrict__ btg,
    const int* __restrict__ shiftp, float* __restrict__ outg) {

  __shared__ WaveBuf wb[4];
  __shared__ float bias_lds[226];

  const int tid  = threadIdx.x;
  const int wave = tid >> 6;
  const int lane = tid & 63;
  const int quad = lane >> 4;
  const int c16  = lane & 15;

  // grid: bid = ((b*8 + head)*16 + wh)*4 + wg ; block owns ww = wg*4 + {0..3}
  const int bid  = blockIdx.x;
  const int wg   = bid & 3;
  const int wh   = (bid >> 2) & 15;
  const int th   = bid >> 6;
  const int head = th & (NHEADS - 1);
  const int b    = th >> 3;
  const int ww   = wg * 4 + wave;

  const int sh   = *shiftp;
  const int base = (b * CCH + head * HDIM) * HWSZ;

  // ---- V prefetch: issue all 8 float4 loads FIRST so they are in flight
  //      during K/Q staging + barrier + GEMM1 (T14 issue-early/write-late) ----
  f32x4 vf[8];
  {
    const float* vb = vg + base + (wh * WSZ) * WID + wg * 32;
#pragma unroll
    for (int i = 0; i < 8; ++i) {
      const int flat = i * 256 + tid;     // 0..2047
      const int col4 = flat & 7;
      const int row  = (flat >> 3) & 7;
      const int ch   = flat >> 6;
      vf[i] = *(const f32x4*)(vb + ch * HWSZ + row * WID + col4 * 4);
    }
  }

  // bias table for this head (shared across the 4 waves), pre-scaled by log2(e)
  for (int t = tid; t < 225; t += 256)
    bias_lds[t] = btg[t * NHEADS + head] * 1.44269504088896f;

  // ---- cooperative K staging: float4 full-line loads, f16 pack, swizzled
  //      uint2 writes into [ch][unit^P] ----
  {
    const float* kb_g = kg + base + (wh * WSZ) * WID + wg * 32;
#pragma unroll
    for (int i = 0; i < 8; ++i) {
      const int flat = i * 256 + tid;     // 0..2047
      const int col4 = flat & 7;
      const int row  = (flat >> 3) & 7;
      const int ch   = flat >> 6;
      const f32x4 f = *(const f32x4*)(kb_g + ch * HWSZ + row * WID + col4 * 4);
      const int w  = col4 >> 1;                       // target window in group
      const int un = (2 * row + (col4 & 1)) ^ (((ch >> 3) << 2) | (ch & 3));
      uint2 u;
      u.x = h2u(__builtin_amdgcn_cvt_pkrtz(f.x, f.y));
      u.y = h2u(__builtin_amdgcn_cvt_pkrtz(f.z, f.w));
      *(uint2*)&wb[w].kq.k[ch * 72 + un * 4] = u;
    }
  }

  // ---- cooperative Q staging (shifted source coords). Vector path valid
  //      whenever sh%4==0 (groups stay 16B-contiguous mod the roll). ----
  if ((sh & 3) == 0) {
#pragma unroll
    for (int i = 0; i < 8; ++i) {
      const int flat = i * 256 + tid;
      const int col4 = flat & 7;
      const int row  = (flat >> 3) & 7;
      const int ch   = flat >> 6;
      const int grow = (wh * WSZ + row + sh) & (HGT - 1);
      const int gc0  = (wg * 32 + col4 * 4 + sh) & (WID - 1);
      const f32x4 f = *(const f32x4*)(qg + base + ch * HWSZ + grow * WID + gc0);
      const int w  = col4 >> 1;
      const int un = (2 * row + (col4 & 1)) ^ (((ch >> 3) << 2) | (ch & 3));
      uint2 u;
      u.x = h2u(__builtin_amdgcn_cvt_pkrtz(f.x, f.y));
      u.y = h2u(__builtin_amdgcn_cvt_pkrtz(f.z, f.w));
      *(uint2*)&wb[w].kq.q[ch * 72 + un * 4] = u;
    }
  } else {  // general-shift fallback: per-element wrap, scalar loads
#pragma unroll
    for (int i = 0; i < 8; ++i) {
      const int flat = i * 256 + tid;
      const int col4 = flat & 7;
      const int row  = (flat >> 3) & 7;
      const int ch   = flat >> 6;
      const int grow = (wh * WSZ + row + sh) & (HGT - 1);
      const float* qrow = qg + base + ch * HWSZ + grow * WID;
      const int cb = wg * 32 + col4 * 4 + sh;
      const float x0 = qrow[(cb + 0) & (WID - 1)];
      const float x1 = qrow[(cb + 1) & (WID - 1)];
      const float x2 = qrow[(cb + 2) & (WID - 1)];
      const float x3 = qrow[(cb + 3) & (WID - 1)];
      const int w  = col4 >> 1;
      const int un = (2 * row + (col4 & 1)) ^ (((ch >> 3) << 2) | (ch & 3));
      uint2 u;
      u.x = h2u(__builtin_amdgcn_cvt_pkrtz(x0, x1));
      u.y = h2u(__builtin_amdgcn_cvt_pkrtz(x2, x3));
      *(uint2*)&wb[w].kq.q[ch * 72 + un * 4] = u;
    }
  }

  // ---- pack prefetched V to f16 (16 VGPRs held through GEMM1). The vmcnt
  //      wait lands here, overlapped by the 16 K/Q loads issued above; the
  //      barrier below drains vmcnt anyway, so no extra stall is added. ----
  uint2 vu[8];
#pragma unroll
  for (int i = 0; i < 8; ++i) {
    vu[i].x = h2u(__builtin_amdgcn_cvt_pkrtz(vf[i].x, vf[i].y));
    vu[i].y = h2u(__builtin_amdgcn_cvt_pkrtz(vf[i].z, vf[i].w));
  }

  __syncthreads();  // K,Q staged for all 4 windows

  // ---- fragment reads: aK rows=key (A-op), bQ cols=query (B-op).
  //      pos(ch,key) = ch*72 + ((key>>2)^P)*4 + (key&3); key = t*16+c16.
  //      32 distinct banks, 2 lanes each -> conflict-free. ----
  half8 aK[4], bQ[4];
  {
    const _Float16* kb = wb[wave].kq.k;
    const _Float16* qb = wb[wave].kq.q;
#pragma unroll
    for (int j = 0; j < 8; ++j) {
      const int ch = quad * 8 + j;
      const int P  = (quad << 2) | (j & 3);
      const int rb = ch * 72 + (c16 & 3);
#pragma unroll
      for (int t = 0; t < 4; ++t) {
        const int un = ((t * 4 + (c16 >> 2)) ^ P) * 4;
        aK[t][j] = kb[rb + un];
        bQ[t][j] = qb[rb + un];
      }
    }
  }

  const f32x4 zero4 = {0.f, 0.f, 0.f, 0.f};
  const float scale2 = 0.17677669529663687f * 1.44269504088896f; // rsqrt(32)*log2e

  // bias row offsets for this lane's keys: r = tr*16 + quad*4 + reg
  int tsub[4];
#pragma unroll
  for (int reg = 0; reg < 4; ++reg) {
    const int t = quad * 4 + reg;
    tsub[reg] = (t >> 3) * 15 + (t & 7);
  }

  u32 pk01[4][4], pk23[4][4];  // [tr][tc]: packed f16 pairs of exp(S^T) regs {0,1},{2,3}
  float rinv[4];

  // ---- GEMM1 streamed per query tile tc: S^T col-tile -> softmax col-sum -> pack ----
#pragma unroll
  for (int tc = 0; tc < 4; ++tc) {
    f32x4 sc[4];
#pragma unroll
    for (int tr = 0; tr < 4; ++tr)
      sc[tr] = __builtin_amdgcn_mfma_f32_16x16x32_f16(aK[tr], bQ[tc], zero4, 0, 0, 0);
    const int q64 = tc * 16 + c16;
    const int qb  = ((q64 >> 3) + 7) * 15 + (q64 & 7) + 7;
    float e[4][4], s = 0.f;
#pragma unroll
    for (int tr = 0; tr < 4; ++tr)
#pragma unroll
      for (int reg = 0; reg < 4; ++reg) {
        const float ev = __builtin_amdgcn_exp2f(
            fmaf(sc[tr][reg], scale2, bias_lds[qb - tr * 30 - tsub[reg]]));
        e[tr][reg] = ev; s += ev;
      }
    // column sum: lane covers 16 keys; quads hold disjoint key quartets
    s += __shfl_xor(s, 16); s += __shfl_xor(s, 32);
    rinv[tc] = __builtin_amdgcn_rcpf(s);
#pragma unroll
    for (int tr = 0; tr < 4; ++tr) {
      pk01[tr][tc] = h2u(__builtin_amdgcn_cvt_pkrtz(e[tr][0], e[tr][1]));
      pk23[tr][tc] = h2u(__builtin_amdgcn_cvt_pkrtz(e[tr][2], e[tr][3]));
    }
  }

  __syncthreads();  // all waves done with K/Q LDS; V may overwrite the union

  // ---- V commit: pure ds_writes from the prefetched+packed registers ----
  {
#pragma unroll
    for (int i = 0; i < 8; ++i) {
      const int flat = i * 256 + tid;     // 0..2047
      const int col4 = flat & 7;
      const int row  = (flat >> 3) & 7;
      const int ch   = flat >> 6;
      const int w  = col4 >> 1;                  // target window within group
      const int kb = row * 8 + (col4 & 1) * 4;   // key index of first of 4 cols
      *(uint2*)&wb[w].vo.v[ch * VP + kb] = vu[i];
    }
  }

  __syncthreads();  // V staged

  // ---- GEMM2: O^T[ch][q] = V^T (A, LDS) x P^T (B, cross-quad shuffles) ----
  half8 aV[2][2];
#pragma unroll
  for (int mt = 0; mt < 2; ++mt)
#pragma unroll
    for (int kc = 0; kc < 2; ++kc)
      aV[mt][kc] = *(const half8*)&wb[wave].vo.v[(mt * 16 + c16) * VP + kc * 32 + quad * 8];

  // B-frag element j needs pexp[tr=kc*2+(quad>>1)][nt][reg=j&3] from lane
  // (2*(quad&1)+(j>>2))*16 + c16 : same c16, compile-time reg -> shfl + select.
  const int s0 = ((lane & 16) << 1) | c16;
  const int s1 = s0 + 16;
  const bool hi = (lane & 32) != 0;

  f32x4 of2[2][4];
#pragma unroll
  for (int mt = 0; mt < 2; ++mt)
#pragma unroll
    for (int nt = 0; nt < 4; ++nt) of2[mt][nt] = zero4;

#pragma unroll
  for (int nt = 0; nt < 4; ++nt)
#pragma unroll
    for (int kc = 0; kc < 2; ++kc) {
      const int t0 = kc * 2, t1 = kc * 2 + 1;
      const u32 w0a = __shfl(pk01[t0][nt], s0), w0b = __shfl(pk01[t1][nt], s0);
      const u32 w1a = __shfl(pk23[t0][nt], s0), w1b = __shfl(pk23[t1][nt], s0);
      const u32 w2a = __shfl(pk01[t0][nt], s1), w2b = __shfl(pk01[t1][nt], s1);
      const u32 w3a = __shfl(pk23[t0][nt], s1), w3b = __shfl(pk23[t1][nt], s1);
      union { u32 u[4]; half8 h; } bp;
      bp.u[0] = hi ? w0b : w0a;
      bp.u[1] = hi ? w1b : w1a;
      bp.u[2] = hi ? w2b : w2a;
      bp.u[3] = hi ? w3b : w3a;
#pragma unroll
      for (int mt = 0; mt < 2; ++mt)
        of2[mt][nt] = __builtin_amdgcn_mfma_f32_16x16x32_f16(aV[mt][kc], bp.h,
                                                             of2[mt][nt], 0, 0, 0);
    }

  // ---- epilogue: normalize by rinv[query col], transpose via per-wave LDS
  //      (disjoint from V; wave-local fences only), coalesced stores ----
  const int hq = (wh * WSZ + (lane >> 3) + sh) & (HGT - 1);
  const int wq = (ww * WSZ + (lane & 7) + sh) & (WID - 1);
  float* ob = outg + base + hq * WID + wq;
  float* obuf = wb[wave].vo.o;

#pragma unroll
  for (int mt = 0; mt < 2; ++mt) {
    lds_fence();
#pragma unroll
    for (int nt = 0; nt < 4; ++nt)
#pragma unroll
      for (int reg = 0; reg < 4; ++reg)
        obuf[(nt * 16 + c16) * 17 + quad * 4 + reg] = of2[mt][nt][reg] * rinv[nt];
    lds_fence();
#pragma unroll
    for (int c = 0; c < 16; ++c)
      ob[(mt * 16 + c) * HWSZ] = obuf[lane * 17 + c];
  }
}

extern "C" void kernel_launch(void* const* d_in, const int* in_sizes, int n_in,
                              void* d_out, int out_size, void* d_ws, size_t ws_size,
                              hipStream_t stream) {
  const float* q  = (const float*)d_in[0];
  const float* k  = (const float*)d_in[1];
  const float* v  = (const float*)d_in[2];
  const float* bt = (const float*)d_in[3];
  const int*   sh = (const int*)d_in[4];
  float* out = (float*)d_out;

  // 8b x 8heads x 16wh x 4 window-groups = 4096 blocks x 256 threads
  dim3 grid(4096), block(256);
  hipLaunchKernelGGL(wattn_kernel, grid, block, 0, stream, q, k, v, bt, sh, out);
}